// Round 1
// baseline (832.439 us; speedup 1.0000x reference)
//
#include <hip/hip_runtime.h>
#include <math.h>

#define N_NODES 50000
#define N_EDGESC 2000
#define N_INC   200000
#define SEQ     64
#define FEATN   6
#define CH      32
#define OUTF    5
#define SLOPE   0.01f

__device__ __forceinline__ float fast_rcp(float x) { return __builtin_amdgcn_rcpf(x); }
__device__ __forceinline__ float sigm(float x) { return fast_rcp(1.f + __expf(-x)); }
__device__ __forceinline__ float tanh_fast(float x) { return 1.f - 2.f * fast_rcp(1.f + __expf(2.f * x)); }
__device__ __forceinline__ float leaky(float v) { return v > 0.f ? v : SLOPE * v; }

// ---------------- GRU (one 32-lane group per node) + fused theta1 matmul ----------------
__global__ __launch_bounds__(256) void gru_theta_kernel(
    const float* __restrict__ price,
    const float* __restrict__ w_ih, const float* __restrict__ w_hh,
    const float* __restrict__ b_ih, const float* __restrict__ b_hh,
    const float* __restrict__ theta1,
    float* __restrict__ Y)
{
  __shared__ float hbuf[256];
  const int tid  = threadIdx.x;
  const int j    = tid & 31;          // hidden unit owned by this lane
  const int gb   = tid & ~31;         // group base in hbuf
  const int node = (blockIdx.x * 256 + tid) >> 5;

  // per-lane weights in registers
  float whr[CH], whz[CH], whn[CH];
#pragma unroll
  for (int k4 = 0; k4 < 8; ++k4) {
    float4 a = *(const float4*)(w_hh + (j       ) * CH + k4 * 4);
    float4 b = *(const float4*)(w_hh + (j + 32  ) * CH + k4 * 4);
    float4 c = *(const float4*)(w_hh + (j + 64  ) * CH + k4 * 4);
    whr[4*k4+0]=a.x; whr[4*k4+1]=a.y; whr[4*k4+2]=a.z; whr[4*k4+3]=a.w;
    whz[4*k4+0]=b.x; whz[4*k4+1]=b.y; whz[4*k4+2]=b.z; whz[4*k4+3]=b.w;
    whn[4*k4+0]=c.x; whn[4*k4+1]=c.y; whn[4*k4+2]=c.z; whn[4*k4+3]=c.w;
  }
  float wir[FEATN], wiz[FEATN], win[FEATN];
#pragma unroll
  for (int f = 0; f < FEATN; ++f) {
    wir[f] = w_ih[(j      ) * FEATN + f];
    wiz[f] = w_ih[(j + 32 ) * FEATN + f];
    win[f] = w_ih[(j + 64 ) * FEATN + f];
  }
  const float br  = b_ih[j]      + b_hh[j];
  const float bz  = b_ih[j + 32] + b_hh[j + 32];
  const float bin = b_ih[j + 64];
  const float bhn = b_hh[j + 64];

  float h = 0.f;
  const float* xp = price + node * (SEQ * FEATN);

  for (int t = 0; t < SEQ; ++t) {
    float2 x01 = *(const float2*)(xp + t * FEATN);
    float2 x23 = *(const float2*)(xp + t * FEATN + 2);
    float2 x45 = *(const float2*)(xp + t * FEATN + 4);

    float gr0 = br + wir[0]*x01.x + wir[1]*x01.y;
    float gr1 =      wir[2]*x23.x + wir[3]*x23.y + wir[4]*x45.x + wir[5]*x45.y;
    float gz0 = bz + wiz[0]*x01.x + wiz[1]*x01.y;
    float gz1 =      wiz[2]*x23.x + wiz[3]*x23.y + wiz[4]*x45.x + wiz[5]*x45.y;
    float gn  = bin + win[0]*x01.x + win[1]*x01.y + win[2]*x23.x
                    + win[3]*x23.y + win[4]*x45.x + win[5]*x45.y;
    float hn0 = bhn, hn1 = 0.f;

    hbuf[tid] = h;  // wave-lockstep: in-order DS pipe + may-alias keeps ordering
#pragma unroll
    for (int k4 = 0; k4 < 8; ++k4) {
      float4 hv = *(const float4*)(hbuf + gb + 4 * k4);
      gr0 += whr[4*k4+0]*hv.x; gr1 += whr[4*k4+1]*hv.y;
      gr0 += whr[4*k4+2]*hv.z; gr1 += whr[4*k4+3]*hv.w;
      gz0 += whz[4*k4+0]*hv.x; gz1 += whz[4*k4+1]*hv.y;
      gz0 += whz[4*k4+2]*hv.z; gz1 += whz[4*k4+3]*hv.w;
      hn0 += whn[4*k4+0]*hv.x; hn1 += whn[4*k4+1]*hv.y;
      hn0 += whn[4*k4+2]*hv.z; hn1 += whn[4*k4+3]*hv.w;
    }
    float r = sigm(gr0 + gr1);
    float z = sigm(gz0 + gz1);
    float n = tanh_fast(gn + r * (hn0 + hn1));
    h = (1.f - z) * n + z * h;
  }

  // epilogue: y_j = sum_k h_k * theta1[j,k]
  hbuf[tid] = h;
  float a0 = 0.f, a1 = 0.f;
#pragma unroll
  for (int k4 = 0; k4 < 8; ++k4) {
    float4 hv = *(const float4*)(hbuf + gb + 4 * k4);
    float4 tv = *(const float4*)(theta1 + j * CH + 4 * k4);
    a0 += tv.x * hv.x + tv.z * hv.z;
    a1 += tv.y * hv.y + tv.w * hv.w;
  }
  Y[node * CH + j] = a0 + a1;
}

// ---------------- degree counting ----------------
__global__ __launch_bounds__(256) void deg_kernel(
    const int* __restrict__ nodes, const int* __restrict__ edges,
    int* __restrict__ DN, int* __restrict__ DE)
{
  int i = blockIdx.x * 256 + threadIdx.x;
  if (i < N_INC) {
    atomicAdd(&DN[nodes[i]], 1);
    atomicAdd(&DE[edges[i]], 1);
  }
}

// ---------------- exclusive scan of edge degrees (single block) ----------------
__global__ __launch_bounds__(256) void scan_kernel(const int* __restrict__ DE, int* __restrict__ OFF)
{
  __shared__ int part[256];
  int t = threadIdx.x;
  int c[8]; int sum = 0;
#pragma unroll
  for (int u = 0; u < 8; ++u) {
    int idx = t * 8 + u;
    int x = (idx < N_EDGESC) ? DE[idx] : 0;
    c[u] = x; sum += x;
  }
  part[t] = sum;
  __syncthreads();
  for (int d = 1; d < 256; d <<= 1) {
    int v = (t >= d) ? part[t - d] : 0;
    __syncthreads();
    part[t] += v;
    __syncthreads();
  }
  int base = part[t] - sum;  // exclusive
#pragma unroll
  for (int u = 0; u < 8; ++u) {
    int idx = t * 8 + u;
    if (idx <= N_EDGESC) OFF[idx] = base;
    base += c[u];
  }
}

// ---------------- node->edge segmented gather-sum (one block per edge) ----------------
__global__ __launch_bounds__(128) void edge_gather_kernel(
    const float* __restrict__ X, const int* __restrict__ nodes,
    const int* __restrict__ OFF, float* __restrict__ EF)
{
  int e = blockIdx.x;
  int s = OFF[e], tE = OFF[e + 1];
  int f = threadIdx.x & 31, g = threadIdx.x >> 5;
  float acc = 0.f;
  for (int i = s + g; i < tE; i += 4)
    acc += X[nodes[i] * CH + f];
  acc += __shfl_down(acc, 32);
  __shared__ float red[32];
  if (threadIdx.x >= 64 && threadIdx.x < 96) red[f] = acc;
  __syncthreads();
  if (threadIdx.x < 32) {
    int cnt = tE - s;
    float binv = cnt > 0 ? 1.f / (float)cnt : 0.f;
    EF[e * CH + f] = (acc + red[f]) * binv;
  }
}

// ---------------- edge->node scatter (atomic) ----------------
__global__ __launch_bounds__(256) void scatter_kernel(
    const float* __restrict__ EF, const int* __restrict__ nodes,
    const int* __restrict__ edges, float* __restrict__ ACC)
{
  int gid = blockIdx.x * 256 + threadIdx.x;
  if (gid >= N_INC * 8) return;
  int i = gid >> 3, q = gid & 7;
  int e = edges[i], n = nodes[i];
  float4 v = *(const float4*)(EF + e * CH + q * 4);
  float* dst = ACC + n * CH + q * 4;
  unsafeAtomicAdd(dst + 0, v.x);
  unsafeAtomicAdd(dst + 1, v.y);
  unsafeAtomicAdd(dst + 2, v.z);
  unsafeAtomicAdd(dst + 3, v.w);
}

// ---------------- dinv+bias+leaky then theta2 matmul (8 threads per node) ----------------
__global__ __launch_bounds__(256) void fuse_theta_kernel(
    const float* __restrict__ ACC, const int* __restrict__ DN,
    const float* __restrict__ bias, const float* __restrict__ theta,
    float* __restrict__ Yout)
{
  int gid = blockIdx.x * 256 + threadIdx.x;
  if (gid >= N_NODES * 8) return;
  int n = gid >> 3, oq = gid & 7;
  int d = DN[n];
  float dinv = d > 0 ? 1.f / (float)d : 0.f;
  float v[CH];
#pragma unroll
  for (int k4 = 0; k4 < 8; ++k4) {
    float4 a = *(const float4*)(ACC + n * CH + 4 * k4);
    v[4*k4+0] = leaky(fmaf(a.x, dinv, bias[4*k4+0]));
    v[4*k4+1] = leaky(fmaf(a.y, dinv, bias[4*k4+1]));
    v[4*k4+2] = leaky(fmaf(a.z, dinv, bias[4*k4+2]));
    v[4*k4+3] = leaky(fmaf(a.w, dinv, bias[4*k4+3]));
  }
  float o[4];
#pragma unroll
  for (int r = 0; r < 4; ++r) {
    float s0 = 0.f, s1 = 0.f;
#pragma unroll
    for (int k4 = 0; k4 < 8; ++k4) {
      float4 tv = *(const float4*)(theta + (oq * 4 + r) * CH + 4 * k4);
      s0 += tv.x * v[4*k4+0] + tv.z * v[4*k4+2];
      s1 += tv.y * v[4*k4+1] + tv.w * v[4*k4+3];
    }
    o[r] = s0 + s1;
  }
  *(float4*)(Yout + n * CH + oq * 4) = make_float4(o[0], o[1], o[2], o[3]);
}

// ---------------- conv2 finalize + output linear ----------------
__global__ __launch_bounds__(256) void out_kernel(
    const float* __restrict__ ACC, const int* __restrict__ DN,
    const float* __restrict__ bias2, const float* __restrict__ w_out,
    const float* __restrict__ b_out, float* __restrict__ out)
{
  int n = blockIdx.x * 256 + threadIdx.x;
  if (n >= N_NODES) return;
  int d = DN[n];
  float dinv = d > 0 ? 1.f / (float)d : 0.f;
  float v[CH];
#pragma unroll
  for (int k4 = 0; k4 < 8; ++k4) {
    float4 a = *(const float4*)(ACC + n * CH + 4 * k4);
    v[4*k4+0] = leaky(fmaf(a.x, dinv, bias2[4*k4+0]));
    v[4*k4+1] = leaky(fmaf(a.y, dinv, bias2[4*k4+1]));
    v[4*k4+2] = leaky(fmaf(a.z, dinv, bias2[4*k4+2]));
    v[4*k4+3] = leaky(fmaf(a.w, dinv, bias2[4*k4+3]));
  }
#pragma unroll
  for (int o = 0; o < OUTF; ++o) {
    float s = b_out[o];
#pragma unroll
    for (int k = 0; k < CH; ++k) s += v[k] * w_out[o * CH + k];
    out[n * OUTF + o] = leaky(s);
  }
}

extern "C" void kernel_launch(void* const* d_in, const int* in_sizes, int n_in,
                              void* d_out, int out_size, void* d_ws, size_t ws_size,
                              hipStream_t stream)
{
  const float* price   = (const float*)d_in[0];
  const int*   e_nodes = (const int*)d_in[1];
  const int*   e_edges = (const int*)d_in[2];
  // d_in[3]=concept, d_in[4]=volumn, d_in[5]=num_edges : unused by reference math
  const float* w_ih    = (const float*)d_in[6];
  const float* w_hh    = (const float*)d_in[7];
  const float* b_ih    = (const float*)d_in[8];
  const float* b_hh    = (const float*)d_in[9];
  const float* theta1  = (const float*)d_in[10];
  const float* bias1   = (const float*)d_in[11];
  const float* theta2  = (const float*)d_in[12];
  const float* bias2   = (const float*)d_in[13];
  const float* w_out   = (const float*)d_in[14];
  const float* b_out   = (const float*)d_in[15];
  float* out = (float*)d_out;

  float* ws  = (float*)d_ws;
  float* Y   = ws;                 // [50000*32]
  float* ACC = ws + 1600000;       // [50000*32]
  float* EF  = ws + 3200000;       // [2000*32]
  int*   DN  = (int*)(ws + 3264000);  // [50000]
  int*   DE  = DN + N_NODES;          // [2000]
  int*   OFF = DE + N_EDGESC;         // [2001]

  hipMemsetAsync(DN, 0, (N_NODES + N_EDGESC + N_EDGESC + 1) * sizeof(int), stream);
  deg_kernel<<<(N_INC + 255) / 256, 256, 0, stream>>>(e_nodes, e_edges, DN, DE);
  scan_kernel<<<1, 256, 0, stream>>>(DE, OFF);

  gru_theta_kernel<<<(N_NODES * 32) / 256, 256, 0, stream>>>(
      price, w_ih, w_hh, b_ih, b_hh, theta1, Y);

  // conv1: node->edge, edge->node
  edge_gather_kernel<<<N_EDGESC, 128, 0, stream>>>(Y, e_nodes, OFF, EF);
  hipMemsetAsync(ACC, 0, N_NODES * CH * sizeof(float), stream);
  scatter_kernel<<<(N_INC * 8 + 255) / 256, 256, 0, stream>>>(EF, e_nodes, e_edges, ACC);

  // conv1 finalize + theta2
  fuse_theta_kernel<<<(N_NODES * 8 + 255) / 256, 256, 0, stream>>>(ACC, DN, bias1, theta2, Y);

  // conv2: node->edge, edge->node
  edge_gather_kernel<<<N_EDGESC, 128, 0, stream>>>(Y, e_nodes, OFF, EF);
  hipMemsetAsync(ACC, 0, N_NODES * CH * sizeof(float), stream);
  scatter_kernel<<<(N_INC * 8 + 255) / 256, 256, 0, stream>>>(EF, e_nodes, e_edges, ACC);

  // conv2 finalize + output linear
  out_kernel<<<(N_NODES + 255) / 256, 256, 0, stream>>>(ACC, DN, bias2, w_out, b_out, out);
}

// Round 2
// 808.186 us; speedup vs baseline: 1.0300x; 1.0300x over previous
//
#include <hip/hip_runtime.h>
#include <math.h>

#define N_NODES 50000
#define N_EDGESC 2000
#define N_INC   200000
#define SEQ     64
#define FEATN   6
#define CH      32
#define OUTF    5
#define SLOPE   0.01f

__device__ __forceinline__ float fast_rcp(float x) { return __builtin_amdgcn_rcpf(x); }
__device__ __forceinline__ float sigm(float x) { return fast_rcp(1.f + __expf(-x)); }
__device__ __forceinline__ float tanh_fast(float x) { return 1.f - 2.f * fast_rcp(1.f + __expf(2.f * x)); }
__device__ __forceinline__ float leaky(float v) { return v > 0.f ? v : SLOPE * v; }

// ---------------- GRU (one 32-lane group per node) + fused theta1 matmul ----------------
// __launch_bounds__(256, 2): allow up to 256 VGPRs so the 114 weight floats
// stay RESIDENT across the 64-step t-loop (round-1 had VGPR=96 -> weights
// were re-loaded every step, ~3x instruction bloat).
__global__ __launch_bounds__(256, 2) void gru_theta_kernel(
    const float* __restrict__ price,
    const float* __restrict__ w_ih, const float* __restrict__ w_hh,
    const float* __restrict__ b_ih, const float* __restrict__ b_hh,
    const float* __restrict__ theta1,
    float* __restrict__ Y)
{
  __shared__ float hbuf[256];
  const int tid  = threadIdx.x;
  const int j    = tid & 31;          // hidden unit owned by this lane
  const int gb   = tid & ~31;         // group base in hbuf
  const int node = (blockIdx.x * 256 + tid) >> 5;

  // per-lane weights in registers (96 floats)
  float whr[CH], whz[CH], whn[CH];
#pragma unroll
  for (int k4 = 0; k4 < 8; ++k4) {
    float4 a = *(const float4*)(w_hh + (j       ) * CH + k4 * 4);
    float4 b = *(const float4*)(w_hh + (j + 32  ) * CH + k4 * 4);
    float4 c = *(const float4*)(w_hh + (j + 64  ) * CH + k4 * 4);
    whr[4*k4+0]=a.x; whr[4*k4+1]=a.y; whr[4*k4+2]=a.z; whr[4*k4+3]=a.w;
    whz[4*k4+0]=b.x; whz[4*k4+1]=b.y; whz[4*k4+2]=b.z; whz[4*k4+3]=b.w;
    whn[4*k4+0]=c.x; whn[4*k4+1]=c.y; whn[4*k4+2]=c.z; whn[4*k4+3]=c.w;
  }
  float wir[FEATN], wiz[FEATN], win[FEATN];
#pragma unroll
  for (int f = 0; f < FEATN; ++f) {
    wir[f] = w_ih[(j      ) * FEATN + f];
    wiz[f] = w_ih[(j + 32 ) * FEATN + f];
    win[f] = w_ih[(j + 64 ) * FEATN + f];
  }
  const float br  = b_ih[j]      + b_hh[j];
  const float bz  = b_ih[j + 32] + b_hh[j + 32];
  const float bin = b_ih[j + 64];
  const float bhn = b_hh[j + 64];

  float h = 0.f;
  const float* xp = price + node * (SEQ * FEATN);

  // software-pipelined x loads
  float2 x01 = *(const float2*)(xp);
  float2 x23 = *(const float2*)(xp + 2);
  float2 x45 = *(const float2*)(xp + 4);

  for (int t = 0; t < SEQ; ++t) {
    float gr0 = br + wir[0]*x01.x + wir[1]*x01.y;
    float gr1 =      wir[2]*x23.x + wir[3]*x23.y + wir[4]*x45.x + wir[5]*x45.y;
    float gz0 = bz + wiz[0]*x01.x + wiz[1]*x01.y;
    float gz1 =      wiz[2]*x23.x + wiz[3]*x23.y + wiz[4]*x45.x + wiz[5]*x45.y;
    float gn  = bin + win[0]*x01.x + win[1]*x01.y + win[2]*x23.x
                    + win[3]*x23.y + win[4]*x45.x + win[5]*x45.y;
    float hn0 = bhn, hn1 = 0.f;

    // prefetch next step's x (hides VMEM latency under the FMA chain)
    if (t + 1 < SEQ) {
      const float* nxt = xp + (t + 1) * FEATN;
      x01 = *(const float2*)(nxt);
      x23 = *(const float2*)(nxt + 2);
      x45 = *(const float2*)(nxt + 4);
    }

    hbuf[tid] = h;  // wave-lockstep: in-order DS pipe + may-alias keeps ordering
#pragma unroll
    for (int k4 = 0; k4 < 8; ++k4) {
      float4 hv = *(const float4*)(hbuf + gb + 4 * k4);
      gr0 += whr[4*k4+0]*hv.x; gr1 += whr[4*k4+1]*hv.y;
      gr0 += whr[4*k4+2]*hv.z; gr1 += whr[4*k4+3]*hv.w;
      gz0 += whz[4*k4+0]*hv.x; gz1 += whz[4*k4+1]*hv.y;
      gz0 += whz[4*k4+2]*hv.z; gz1 += whz[4*k4+3]*hv.w;
      hn0 += whn[4*k4+0]*hv.x; hn1 += whn[4*k4+1]*hv.y;
      hn0 += whn[4*k4+2]*hv.z; hn1 += whn[4*k4+3]*hv.w;
    }
    float r = sigm(gr0 + gr1);
    float z = sigm(gz0 + gz1);
    float n = tanh_fast(gn + r * (hn0 + hn1));
    h = (1.f - z) * n + z * h;
  }

  // epilogue: y_j = sum_k h_k * theta1[j,k]
  hbuf[tid] = h;
  float a0 = 0.f, a1 = 0.f;
#pragma unroll
  for (int k4 = 0; k4 < 8; ++k4) {
    float4 hv = *(const float4*)(hbuf + gb + 4 * k4);
    float4 tv = *(const float4*)(theta1 + j * CH + 4 * k4);
    a0 += tv.x * hv.x + tv.z * hv.z;
    a1 += tv.y * hv.y + tv.w * hv.w;
  }
  Y[node * CH + j] = a0 + a1;
}

// ---------------- degree counting ----------------
__global__ __launch_bounds__(256) void deg_kernel(
    const int* __restrict__ nodes, const int* __restrict__ edges,
    int* __restrict__ DN, int* __restrict__ DE)
{
  int i = blockIdx.x * 256 + threadIdx.x;
  if (i < N_INC) {
    atomicAdd(&DN[nodes[i]], 1);
    atomicAdd(&DE[edges[i]], 1);
  }
}

// ---------------- exclusive scan of edge degrees (single block) ----------------
__global__ __launch_bounds__(256) void scan_kernel(const int* __restrict__ DE, int* __restrict__ OFF)
{
  __shared__ int part[256];
  int t = threadIdx.x;
  int c[8]; int sum = 0;
#pragma unroll
  for (int u = 0; u < 8; ++u) {
    int idx = t * 8 + u;
    int x = (idx < N_EDGESC) ? DE[idx] : 0;
    c[u] = x; sum += x;
  }
  part[t] = sum;
  __syncthreads();
  for (int d = 1; d < 256; d <<= 1) {
    int v = (t >= d) ? part[t - d] : 0;
    __syncthreads();
    part[t] += v;
    __syncthreads();
  }
  int base = part[t] - sum;  // exclusive
#pragma unroll
  for (int u = 0; u < 8; ++u) {
    int idx = t * 8 + u;
    if (idx <= N_EDGESC) OFF[idx] = base;
    base += c[u];
  }
}

// ---------------- node->edge segmented gather-sum (one block per edge) ----------------
__global__ __launch_bounds__(128) void edge_gather_kernel(
    const float* __restrict__ X, const int* __restrict__ nodes,
    const int* __restrict__ OFF, float* __restrict__ EF)
{
  int e = blockIdx.x;
  int s = OFF[e], tE = OFF[e + 1];
  int f = threadIdx.x & 31, g = threadIdx.x >> 5;
  float acc = 0.f;
  for (int i = s + g; i < tE; i += 4)
    acc += X[nodes[i] * CH + f];
  acc += __shfl_down(acc, 32);
  __shared__ float red[32];
  if (threadIdx.x >= 64 && threadIdx.x < 96) red[f] = acc;
  __syncthreads();
  if (threadIdx.x < 32) {
    int cnt = tE - s;
    float binv = cnt > 0 ? 1.f / (float)cnt : 0.f;
    EF[e * CH + f] = (acc + red[f]) * binv;
  }
}

// ---------------- edge->node scatter (atomic) ----------------
__global__ __launch_bounds__(256) void scatter_kernel(
    const float* __restrict__ EF, const int* __restrict__ nodes,
    const int* __restrict__ edges, float* __restrict__ ACC)
{
  int gid = blockIdx.x * 256 + threadIdx.x;
  if (gid >= N_INC * 8) return;
  int i = gid >> 3, q = gid & 7;
  int e = edges[i], n = nodes[i];
  float4 v = *(const float4*)(EF + e * CH + q * 4);
  float* dst = ACC + n * CH + q * 4;
  unsafeAtomicAdd(dst + 0, v.x);
  unsafeAtomicAdd(dst + 1, v.y);
  unsafeAtomicAdd(dst + 2, v.z);
  unsafeAtomicAdd(dst + 3, v.w);
}

// ---------------- dinv+bias+leaky then theta2 matmul (8 threads per node) ----------------
__global__ __launch_bounds__(256) void fuse_theta_kernel(
    const float* __restrict__ ACC, const int* __restrict__ DN,
    const float* __restrict__ bias, const float* __restrict__ theta,
    float* __restrict__ Yout)
{
  int gid = blockIdx.x * 256 + threadIdx.x;
  if (gid >= N_NODES * 8) return;
  int n = gid >> 3, oq = gid & 7;
  int d = DN[n];
  float dinv = d > 0 ? 1.f / (float)d : 0.f;
  float v[CH];
#pragma unroll
  for (int k4 = 0; k4 < 8; ++k4) {
    float4 a = *(const float4*)(ACC + n * CH + 4 * k4);
    v[4*k4+0] = leaky(fmaf(a.x, dinv, bias[4*k4+0]));
    v[4*k4+1] = leaky(fmaf(a.y, dinv, bias[4*k4+1]));
    v[4*k4+2] = leaky(fmaf(a.z, dinv, bias[4*k4+2]));
    v[4*k4+3] = leaky(fmaf(a.w, dinv, bias[4*k4+3]));
  }
  float o[4];
#pragma unroll
  for (int r = 0; r < 4; ++r) {
    float s0 = 0.f, s1 = 0.f;
#pragma unroll
    for (int k4 = 0; k4 < 8; ++k4) {
      float4 tv = *(const float4*)(theta + (oq * 4 + r) * CH + 4 * k4);
      s0 += tv.x * v[4*k4+0] + tv.z * v[4*k4+2];
      s1 += tv.y * v[4*k4+1] + tv.w * v[4*k4+3];
    }
    o[r] = s0 + s1;
  }
  *(float4*)(Yout + n * CH + oq * 4) = make_float4(o[0], o[1], o[2], o[3]);
}

// ---------------- conv2 finalize + output linear ----------------
__global__ __launch_bounds__(256) void out_kernel(
    const float* __restrict__ ACC, const int* __restrict__ DN,
    const float* __restrict__ bias2, const float* __restrict__ w_out,
    const float* __restrict__ b_out, float* __restrict__ out)
{
  int n = blockIdx.x * 256 + threadIdx.x;
  if (n >= N_NODES) return;
  int d = DN[n];
  float dinv = d > 0 ? 1.f / (float)d : 0.f;
  float v[CH];
#pragma unroll
  for (int k4 = 0; k4 < 8; ++k4) {
    float4 a = *(const float4*)(ACC + n * CH + 4 * k4);
    v[4*k4+0] = leaky(fmaf(a.x, dinv, bias2[4*k4+0]));
    v[4*k4+1] = leaky(fmaf(a.y, dinv, bias2[4*k4+1]));
    v[4*k4+2] = leaky(fmaf(a.z, dinv, bias2[4*k4+2]));
    v[4*k4+3] = leaky(fmaf(a.w, dinv, bias2[4*k4+3]));
  }
#pragma unroll
  for (int o = 0; o < OUTF; ++o) {
    float s = b_out[o];
#pragma unroll
    for (int k = 0; k < CH; ++k) s += v[k] * w_out[o * CH + k];
    out[n * OUTF + o] = leaky(s);
  }
}

extern "C" void kernel_launch(void* const* d_in, const int* in_sizes, int n_in,
                              void* d_out, int out_size, void* d_ws, size_t ws_size,
                              hipStream_t stream)
{
  const float* price   = (const float*)d_in[0];
  const int*   e_nodes = (const int*)d_in[1];
  const int*   e_edges = (const int*)d_in[2];
  // d_in[3]=concept, d_in[4]=volumn, d_in[5]=num_edges : unused by reference math
  const float* w_ih    = (const float*)d_in[6];
  const float* w_hh    = (const float*)d_in[7];
  const float* b_ih    = (const float*)d_in[8];
  const float* b_hh    = (const float*)d_in[9];
  const float* theta1  = (const float*)d_in[10];
  const float* bias1   = (const float*)d_in[11];
  const float* theta2  = (const float*)d_in[12];
  const float* bias2   = (const float*)d_in[13];
  const float* w_out   = (const float*)d_in[14];
  const float* b_out   = (const float*)d_in[15];
  float* out = (float*)d_out;

  float* ws  = (float*)d_ws;
  float* Y   = ws;                 // [50000*32]
  float* ACC = ws + 1600000;       // [50000*32]
  float* EF  = ws + 3200000;       // [2000*32]
  int*   DN  = (int*)(ws + 3264000);  // [50000]
  int*   DE  = DN + N_NODES;          // [2000]
  int*   OFF = DE + N_EDGESC;         // [2001]

  hipMemsetAsync(DN, 0, (N_NODES + N_EDGESC + N_EDGESC + 1) * sizeof(int), stream);
  deg_kernel<<<(N_INC + 255) / 256, 256, 0, stream>>>(e_nodes, e_edges, DN, DE);
  scan_kernel<<<1, 256, 0, stream>>>(DE, OFF);

  gru_theta_kernel<<<(N_NODES * 32) / 256, 256, 0, stream>>>(
      price, w_ih, w_hh, b_ih, b_hh, theta1, Y);

  // conv1: node->edge, edge->node
  edge_gather_kernel<<<N_EDGESC, 128, 0, stream>>>(Y, e_nodes, OFF, EF);
  hipMemsetAsync(ACC, 0, N_NODES * CH * sizeof(float), stream);
  scatter_kernel<<<(N_INC * 8 + 255) / 256, 256, 0, stream>>>(EF, e_nodes, e_edges, ACC);

  // conv1 finalize + theta2
  fuse_theta_kernel<<<(N_NODES * 8 + 255) / 256, 256, 0, stream>>>(ACC, DN, bias1, theta2, Y);

  // conv2: node->edge, edge->node
  edge_gather_kernel<<<N_EDGESC, 128, 0, stream>>>(Y, e_nodes, OFF, EF);
  hipMemsetAsync(ACC, 0, N_NODES * CH * sizeof(float), stream);
  scatter_kernel<<<(N_INC * 8 + 255) / 256, 256, 0, stream>>>(EF, e_nodes, e_edges, ACC);

  // conv2 finalize + output linear
  out_kernel<<<(N_NODES + 255) / 256, 256, 0, stream>>>(ACC, DN, bias2, w_out, b_out, out);
}